// Round 2
// baseline (133.508 us; speedup 1.0000x reference)
//
#include <hip/hip_runtime.h>
#include <hip/hip_bf16.h>
#include <math.h>

#define B_ 2
#define S_ 4096
#define H_ 8
#define D_ 64
#define W_ 512

#define MASKV -1e30f
#define LOG2E 1.4426950408889634f

typedef float f32x4 __attribute__((ext_vector_type(4)));
typedef short s16x4 __attribute__((ext_vector_type(4)));
typedef short s16x8 __attribute__((ext_vector_type(8)));
typedef unsigned int u32;
typedef unsigned int u32x2 __attribute__((ext_vector_type(2)));
typedef unsigned int u32x4 __attribute__((ext_vector_type(4)));
typedef __attribute__((address_space(1))) const u32 as1_u32;
typedef __attribute__((address_space(3))) u32 as3_u32;

__device__ inline short f2bf(float f) {
    unsigned u = __builtin_bit_cast(unsigned, f);
    unsigned r = (u + 0x7FFFu + ((u >> 16) & 1u)) >> 16;
    return (short)r;
}
__device__ inline s16x8 pack8(f32x4 a, f32x4 b) {
    s16x8 r;
    r[0]=f2bf(a[0]); r[1]=f2bf(a[1]); r[2]=f2bf(a[2]); r[3]=f2bf(a[3]);
    r[4]=f2bf(b[0]); r[5]=f2bf(b[1]); r[6]=f2bf(b[2]); r[7]=f2bf(b[3]);
    return r;
}
// packed fp32->bf16 RNE: 1 inst per pair
__device__ __forceinline__ u32 cvtpk_bf16(float a, float b) {
    u32 r;
    asm("v_cvt_pk_bf16_f32 %0, %1, %2" : "=v"(r) : "v"(a), "v"(b));
    return r;
}
// bare 2^x (inputs pre-scaled by log2e at projection/bias-load time)
__device__ __forceinline__ float fexp2(float x) {
    float r;
    asm("v_exp_f32 %0, %1" : "=v"(r) : "v"(x));
    return r;
}
__device__ __forceinline__ void gl_lds16(const void* g, void* l) {
    __builtin_amdgcn_global_load_lds((as1_u32*)(unsigned long long)g,
                                     (as3_u32*)(u32)(unsigned long long)l,
                                     16, 0, 0);
}

// ---------------------------------------------------------------------------
// Pre-pass (shrunk: xs conversion moved into proj's reg-staging):
//   blocks [0,256):    prev_k fp32 -> bf16 flat
//   blocks [256,384):  prev_v -> vbt bf16 [h*64+d][b*4608 + jj]
//   blocks [384,576):  wt[z*512+n][k] = w_z[k][n] * scale_z, bf16
//   q weights carry an extra log2(e) so attn can use bare v_exp_f32.
// ---------------------------------------------------------------------------
__global__ __launch_bounds__(256, 4)
void prep_kernel(const float* __restrict__ pk, const float* __restrict__ pv,
                 const float* __restrict__ wq, const float* __restrict__ wk,
                 const float* __restrict__ wv,
                 short* __restrict__ pkbf, short* __restrict__ vbt,
                 short* __restrict__ wt)
{
    __shared__ char smem[17408];
    const int bid = blockIdx.x;
    const int tid = threadIdx.x;

    if (bid < 256) {
        // ---- convert prev_k (524288 floats) ----
        size_t i8 = ((size_t)bid * 256 + tid) * 8;
        f32x4 a = *(const f32x4*)(pk + i8);
        f32x4 b = *(const f32x4*)(pk + i8 + 4);
        *(s16x8*)(pkbf + i8) = pack8(a, b);
    } else if (bid < 384) {
        // ---- prev_v transpose ----
        short (*st)[72] = (short(*)[72])smem;
        const int b2 = bid - 256;
        const int jt = b2 & 7, h = (b2 >> 3) & 7, b = b2 >> 6;
        const int jj0 = jt * 64;
        {
            int kk = tid >> 2, d0 = (tid & 3) * 16;
            const float* src = pv + (((size_t)(b * 512 + jj0 + kk)) * 8 + h) * 64 + d0;
            f32x4 x0 = *(const f32x4*)(src);
            f32x4 x1 = *(const f32x4*)(src + 4);
            f32x4 x2 = *(const f32x4*)(src + 8);
            f32x4 x3 = *(const f32x4*)(src + 12);
            *(s16x8*)&st[kk][d0]     = pack8(x0, x1);
            *(s16x8*)&st[kk][d0 + 8] = pack8(x2, x3);
        }
        __syncthreads();
        {
            int dd = tid >> 2, k0 = (tid & 3) * 16;
            s16x8 o0, o1;
            #pragma unroll
            for (int t = 0; t < 8; ++t) { o0[t] = st[k0 + t][dd]; o1[t] = st[k0 + 8 + t][dd]; }
            short* dst = vbt + (size_t)(h * 64 + dd) * 9216 + b * 4608 + jj0 + k0;
            *(s16x8*)dst = o0;
            *(s16x8*)(dst + 8) = o1;
        }
    } else {
        // ---- weight transpose ----
        float (*st)[68] = (float(*)[68])smem;
        const int t2 = bid - 384;
        const int k0 = (t2 & 7) * 64;
        const int nt = t2 >> 3;
        const int z  = nt >> 3;
        const int n0 = (nt & 7) * 64;
        const float* wz = (z == 0) ? wq : (z == 1) ? wk : wv;
        const float scale = (z == 0) ? 0.125f * LOG2E : 1.0f;
        {
            int kk = tid >> 4, nn = (tid & 15) * 4;
            #pragma unroll
            for (int it = 0; it < 4; ++it) {
                f32x4 x = *(const f32x4*)(wz + (size_t)(k0 + kk + it * 16) * 512 + n0 + nn);
                *(f32x4*)&st[kk + it * 16][nn] = x;
            }
        }
        __syncthreads();
        {
            int nn2 = tid >> 2, kseg = (tid & 3) * 16;
            s16x8 o0, o1;
            #pragma unroll
            for (int j = 0; j < 8; ++j) o0[j] = f2bf(st[kseg + j][nn2] * scale);
            #pragma unroll
            for (int j = 0; j < 8; ++j) o1[j] = f2bf(st[kseg + 8 + j][nn2] * scale);
            short* dst = wt + (size_t)(z * 512 + n0 + nn2) * 512 + k0 + kseg;
            *(s16x8*)(dst) = o0;
            *(s16x8*)(dst + 8) = o1;
        }
    }
}

// ---------------------------------------------------------------------------
// Fused QKV projection. X is read DIRECTLY from fp32 xs (no pre-conversion
// pass): global->reg, cvt_pk->bf16, ds_write with the same XOR-granule
// swizzle. W stays gl_lds16 from the bf16 wt. BK=32 double-buffered, one
// barrier per step; __syncthreads' implicit vmcnt(0)/lgkmcnt(0) provides the
// staging drain. (256,3): grid is exactly 3 blocks/CU, so allow 170 VGPRs.
// ---------------------------------------------------------------------------
__global__ __launch_bounds__(256, 3)
void proj_kernel(const float* __restrict__ xs, const short* __restrict__ wt,
                 short* __restrict__ qkbf, short* __restrict__ vbt,
                 float* __restrict__ out)
{
    __shared__ short Xs[2][128][32];
    __shared__ short Ws[2][128][32];

    const int tid = threadIdx.x;
    const int m0  = blockIdx.x * 128;
    const int n0  = blockIdx.y * 128;
    const int z   = n0 >> 9;
    const int ln0 = n0 & 511;
    const int wave = tid >> 6, lane = tid & 63;
    const int wq = (wave & 1) * 64;
    const int wx = (wave >> 1) * 64;
    const int lr = lane & 15, quad = lane >> 4;

    f32x4 acc[4][4] = {};

    const int r4 = lane >> 2;      // 16 rows per issue (64 B rows)
    const int g4 = lane & 3;       // 4 granules of 8 elems per row

    // W stage: async global->LDS, source pre-swizzled so LDS slot g holds
    // global granule g ^ (row&3); read side applies the same XOR.
    auto stageW = [&](int s, int buf) {
        const int k0 = s * 32;
        #pragma unroll
        for (int i = 0; i < 2; ++i) {
            int row = 32 * wave + 16 * i + r4;
            int gs  = g4 ^ (row & 3);
            gl_lds16(wt + (size_t)(n0 + row) * 512 + k0 + gs * 8,
                     &Ws[buf][32 * wave + 16 * i][0]);
        }
    };
    // X stage: fp32 global -> regs (8 floats/lane/iter)
    f32x4 xr[4];
    auto loadX = [&](int s) {
        const int k0 = s * 32;
        #pragma unroll
        for (int i = 0; i < 2; ++i) {
            int row = 32 * wave + 16 * i + r4;
            int gs  = g4 ^ (row & 3);
            const float* p = xs + (size_t)(m0 + row) * 512 + k0 + gs * 8;
            xr[2 * i]     = *(const f32x4*)(p);
            xr[2 * i + 1] = *(const f32x4*)(p + 4);
        }
    };
    // regs -> bf16 -> LDS (slot g4 holds global granule g4^(row&3), matching W)
    auto writeX = [&](int buf) {
        #pragma unroll
        for (int i = 0; i < 2; ++i) {
            int row = 32 * wave + 16 * i + r4;
            u32x4 o;
            o[0] = cvtpk_bf16(xr[2*i][0],   xr[2*i][1]);
            o[1] = cvtpk_bf16(xr[2*i][2],   xr[2*i][3]);
            o[2] = cvtpk_bf16(xr[2*i+1][0], xr[2*i+1][1]);
            o[3] = cvtpk_bf16(xr[2*i+1][2], xr[2*i+1][3]);
            *(u32x4*)&Xs[buf][row][g4 * 8] = o;
        }
    };

    stageW(0, 0);
    loadX(0);
    writeX(0);
    __syncthreads();                      // drains vmcnt (W0) + lgkm (X0 writes)

    for (int s = 0; s < 16; ++s) {
        const int buf = s & 1;
        if (s < 15) { stageW(s + 1, buf ^ 1); loadX(s + 1); }

        s16x8 af[4], bf[4];
        #pragma unroll
        for (int ta = 0; ta < 4; ++ta) {
            int R = wq + ta * 16 + lr;
            af[ta] = *(const s16x8*)&Ws[buf][R][((quad ^ (R & 3)) * 8)];
        }
        #pragma unroll
        for (int tb = 0; tb < 4; ++tb) {
            int R = wx + tb * 16 + lr;
            bf[tb] = *(const s16x8*)&Xs[buf][R][((quad ^ (R & 3)) * 8)];
        }
        #pragma unroll
        for (int ta = 0; ta < 4; ++ta)
            #pragma unroll
            for (int tb = 0; tb < 4; ++tb)
                acc[ta][tb] = __builtin_amdgcn_mfma_f32_16x16x32_bf16(
                    af[ta], bf[tb], acc[ta][tb], 0, 0, 0);

        if (s < 15) {
            writeX(buf ^ 1);              // buf^1 free since previous barrier
            __syncthreads();              // drains W(s+1) vmcnt + X writes
        }
    }

    #pragma unroll
    for (int ta = 0; ta < 4; ++ta)
        #pragma unroll
        for (int tb = 0; tb < 4; ++tb) {
            int m  = m0 + wx + tb * 16 + lr;
            int ln = ln0 + wq + ta * 16 + quad * 4;
            int bb = m >> 12, seq = m & 4095;
            if (z < 2) {
                short* base = qkbf + (size_t)z * ((size_t)8192 * 512);
                u32x2 o;
                o[0] = cvtpk_bf16(acc[ta][tb][0], acc[ta][tb][1]);
                o[1] = cvtpk_bf16(acc[ta][tb][2], acc[ta][tb][3]);
                *(u32x2*)(base + (size_t)m * 512 + ln) = o;
                if (z == 1 && seq >= 3584) {
                    float* dst = out + 4194304 + ((size_t)(bb * 512 + seq - 3584)) * 512 + ln;
                    *(f32x4*)dst = acc[ta][tb];
                }
            } else {
                size_t col = (size_t)bb * 4608 + 512 + seq;
                #pragma unroll
                for (int g = 0; g < 4; ++g)
                    vbt[(size_t)(ln + g) * 9216 + col] = f2bf(acc[ta][tb][g]);
                if (seq >= 3584) {
                    float* dst = out + 4194304 + 524288 + ((size_t)(bb * 512 + seq - 3584)) * 512 + ln;
                    *(f32x4*)dst = acc[ta][tb];
                }
            }
        }
}

// ---------------------------------------------------------------------------
// MFMA flash attention. Depth-2 staging pipeline: 3 LDS buffers, raw
// s_barrier + counted s_waitcnt vmcnt(2) so chunk c+1's loads stay in flight
// across the barrier (chunk c+2 issued after it). No vmcnt(0) drain in the
// main loop. XCD-bijective block swizzle co-locates the 4 qt-blocks of each
// (b,n,h) on one XCD (K/V L2 reuse; per-XCD footprint ~2.6 MB < 4 MB L2).
// ---------------------------------------------------------------------------
__global__ __launch_bounds__(512, 4)
void attn_kernel(const short* __restrict__ qkbf, const short* __restrict__ vbt,
                 const short* __restrict__ pkbf, const float* __restrict__ rel_bias,
                 float* __restrict__ out)
{
    __shared__ short k_s[3][64][64];     // [buf][key][d], XOR-swizzled granules
    __shared__ short vt_s[3][64][64];    // [buf][d][key], XOR-swizzled granules
    __shared__ short p_s[128][64];       // per-wave P rows, XOR-swizzled
    __shared__ float bias_s[512];

    const short* qb = qkbf;
    const short* kb = qkbf + (size_t)8192 * 512;

    // XCD swizzle: xcd = bid&7; 4 consecutive slots on one XCD share (b,n,h)
    const int bid = blockIdx.x;
    const int slot = bid >> 3;
    const int qt  = slot & 3;
    const int grp = (bid & 7) * 16 + (slot >> 2);   // [0,128)
    const int h = grp & 7;
    const int n = (grp >> 3) & 7;
    const int b = grp >> 6;

    const int tid = threadIdx.x;
    const int wave = tid >> 6, lane = tid & 63;
    const int lr = lane & 15, quad = lane >> 4;
    const int q0 = qt * 128;
    const int i0 = q0 + 16 * wave;

    // T5 bias table (512 entries, one per thread), pre-scaled by log2(e)
    {
        int nd = tid;
        int bucket;
        if (nd < 16) bucket = nd;
        else {
            int vbk = 16 + (int)(log((double)nd * (1.0 / 16.0)) * (16.0 / log(8.0)));
            bucket = vbk < 31 ? vbk : 31;
        }
        bias_s[nd] = rel_bias[h * 32 + bucket] * LOG2E;
    }
    const float bias31 = rel_bias[h * 32 + 31] * LOG2E;

    // Q B-frag direct from global
    s16x8 aq[2];
    {
        const short* src = qb + (size_t)(b * S_ + n * W_ + i0 + lr) * 512 + h * 64 + quad * 8;
        aq[0] = *(const s16x8*)(src);
        aq[1] = *(const s16x8*)(src + 32);
    }

    f32x4 oacc[4] = {};
    float lsum = 0.f;

    const int cmin = (16 * wave) >> 6;
    const int cmax = (16 * wave + 527) >> 6;

    const int r8 = lane >> 3, gr = lane & 7;

    // wave w stages rows 8w..8w+7 of K chunk and of V^T chunk
    auto issueKV = [&](int c, int pb) {
        int jj = q0 + 64 * c + 8 * wave + r8;          // key in [q0, q0+640)
        int p  = n * W_ + jj - W_;
        int gs = gr ^ r8;
        const short* ksrc = (p >= 0)
            ? kb   + ((size_t)(b * S_ + p)) * 512 + h * 64 + gs * 8
            : pkbf + (((size_t)(b * W_ + jj)) * 8 + h) * 64 + gs * 8;
        gl_lds16(ksrc, &k_s[pb][8 * wave][0]);
        int drow = 8 * wave + r8;
        const short* vsrc = vbt + (size_t)(h * 64 + drow) * 9216
                          + b * 4608 + n * W_ + q0 + 64 * c + gs * 8;
        gl_lds16(vsrc, &vt_s[pb][8 * wave][0]);
    };

    __syncthreads();            // bias_s visible; drains prologue vmem loads
    issueKV(0, 0);
    issueKV(1, 1);

    for (int c = 0; c < 10; ++c) {
        const int pb = c % 3;
        // chunk c landed (2 loads/wave/chunk; chunk c+1's 2 stay in flight)
        if (c < 9) { asm volatile("s_waitcnt vmcnt(2)" ::: "memory"); }
        else       { asm volatile("s_waitcnt vmcnt(0)" ::: "memory"); }
        __builtin_amdgcn_s_barrier();        // all waves' chunk-c rows valid
        __builtin_amdgcn_sched_barrier(0);
        if (c < 8) issueKV(c + 2, (c + 2) % 3);
        if (c < cmin || c > cmax) continue;

        // ---- S^T = K * Q^T : D[key][q], col=lane&15=q, row=quad*4+rg=key ----
        f32x4 sacc[4] = {};
        #pragma unroll
        for (int ks = 0; ks < 2; ++ks) {
            s16x8 bk[4];
            #pragma unroll
            for (int tn = 0; tn < 4; ++tn)
                bk[tn] = *(const s16x8*)&k_s[pb][tn * 16 + lr][(((4 * ks + quad) ^ (lr & 7)) * 8)];
            #pragma unroll
            for (int tn = 0; tn < 4; ++tn)
                sacc[tn] = __builtin_amdgcn_mfma_f32_16x16x32_bf16(
                    bk[tn], aq[ks], sacc[tn], 0, 0, 0);
        }

        // ---- bias + mask + exp2 (fixed-max softmax) ----
        const int ib = i0 + lr;          // this lane's q row (window coords)
        const int jb = q0 + 64 * c;
        if (64 * c - 16 * wave <= 336) {
            // all valid pairs have nd >= 113 -> bucket 31 (constant bias)
            #pragma unroll
            for (int tn = 0; tn < 4; ++tn) {
                float pv[4];
                #pragma unroll
                for (int rg = 0; rg < 4; ++rg) {
                    int j = jb + tn * 16 + quad * 4 + rg;
                    unsigned dm1 = (unsigned)(j - ib - 1);
                    float sv = (dm1 < 512u) ? (sacc[tn][rg] + bias31) : MASKV;
                    float p = fexp2(sv);
                    lsum += p;
                    pv[rg] = p;
                }
                u32x2 pp;
                pp[0] = cvtpk_bf16(pv[0], pv[1]);
                pp[1] = cvtpk_bf16(pv[2], pv[3]);
                int gp = (2 * tn + (quad >> 1)) ^ (lr & 7);
                *(u32x2*)&p_s[16 * wave + lr][gp * 8 + (quad & 1) * 4] = pp;
            }
        } else {
            #pragma unroll
            for (int tn = 0; tn < 4; ++tn) {
                float pv[4];
                #pragma unroll
                for (int rg = 0; rg < 4; ++rg) {
                    int j = jb + tn * 16 + quad * 4 + rg;
                    unsigned dm1 = (unsigned)(j - ib - 1);
                    float bias = bias_s[(ib + 512 - j) & 511];
                    float sv = (dm1 < 512u) ? (sacc[tn][rg] + bias) : MASKV;
                    float p = fexp2(sv);
                    lsum += p;
                    pv[rg] = p;
                }
                u32x2 pp;
                pp[0] = cvtpk_bf16(pv[0], pv[1]);
                pp[1] = cvtpk_bf16(pv[2], pv[3]);
                int gp = (2 * tn + (quad >> 1)) ^ (lr & 7);
                *(u32x2*)&p_s[16 * wave + lr][gp * 8 + (quad & 1) * 4] = pp;
            }
        }

        asm volatile("s_waitcnt lgkmcnt(0)" ::: "memory");

        // ---- O += P V : A=P (q x keys), B=V (keys x d) ----
        #pragma unroll
        for (int ks = 0; ks < 2; ++ks) {
            int gpa = (4 * ks + quad) ^ (lr & 7);
            s16x8 ap = *(const s16x8*)&p_s[16 * wave + lr][gpa * 8];
            s16x8 bv[4];
            #pragma unroll
            for (int tn = 0; tn < 4; ++tn)
                bv[tn] = *(const s16x8*)&vt_s[pb][tn * 16 + lr][(((4 * ks + quad) ^ (lr & 7)) * 8)];
            #pragma unroll
            for (int tn = 0; tn < 4; ++tn)
                oacc[tn] = __builtin_amdgcn_mfma_f32_16x16x32_bf16(
                    ap, bv[tn], oacc[tn], 0, 0, 0);
        }
    }

    // ---- final l reduction over quads; redistribute; store ----
    lsum += __shfl_xor(lsum, 16);
    lsum += __shfl_xor(lsum, 32);
    float linv[4];
    #pragma unroll
    for (int rg = 0; rg < 4; ++rg)
        linv[rg] = 1.0f / __shfl(lsum, quad * 4 + rg);

    #pragma unroll
    for (int rg = 0; rg < 4; ++rg) {
        int row = i0 + quad * 4 + rg;
        float* dst = out + (((size_t)b * S_ + n * W_ + row) * H_ + h) * D_ + lr;
        #pragma unroll
        for (int tn = 0; tn < 4; ++tn)
            dst[tn * 16] = oacc[tn][rg] * linv[rg];
    }
}

extern "C" void kernel_launch(void* const* d_in, const int* in_sizes, int n_in,
                              void* d_out, int out_size, void* d_ws, size_t ws_size,
                              hipStream_t stream)
{
    const float* xs       = (const float*)d_in[0];
    const float* prev_k   = (const float*)d_in[1];
    const float* prev_v   = (const float*)d_in[2];
    const float* w_q      = (const float*)d_in[3];
    const float* w_k      = (const float*)d_in[4];
    const float* w_v      = (const float*)d_in[5];
    const float* rel_bias = (const float*)d_in[6];
    float* out = (float*)d_out;

    short* wt   = (short*)d_ws;                         //   786,432
    short* qkbf = wt   + (size_t)786432;                // 8,388,608 (q then k)
    short* pkbf = qkbf + (size_t)8388608;               //   524,288
    short* vbt  = pkbf + (size_t)524288;                // 512 x 9216

    prep_kernel<<<576, 256, 0, stream>>>(prev_k, prev_v, w_q, w_k, w_v,
                                         pkbf, vbt, wt);

    proj_kernel<<<dim3(64, 12), 256, 0, stream>>>(xs, wt, qkbf, vbt, out);

    attn_kernel<<<512, 512, 0, stream>>>(qkbf, vbt, pkbf, rel_bias, out);
}

// Round 3
// 127.545 us; speedup vs baseline: 1.0468x; 1.0468x over previous
//
#include <hip/hip_runtime.h>
#include <hip/hip_bf16.h>
#include <math.h>

#define B_ 2
#define S_ 4096
#define H_ 8
#define D_ 64
#define W_ 512

#define MASKV -1e30f
#define LOG2E 1.4426950408889634f

typedef float f32x4 __attribute__((ext_vector_type(4)));
typedef short s16x4 __attribute__((ext_vector_type(4)));
typedef short s16x8 __attribute__((ext_vector_type(8)));
typedef unsigned int u32;
typedef unsigned int u32x2 __attribute__((ext_vector_type(2)));
typedef __attribute__((address_space(1))) const u32 as1_u32;
typedef __attribute__((address_space(3))) u32 as3_u32;

__device__ inline short f2bf(float f) {
    unsigned u = __builtin_bit_cast(unsigned, f);
    unsigned r = (u + 0x7FFFu + ((u >> 16) & 1u)) >> 16;
    return (short)r;
}
__device__ inline s16x8 pack8(f32x4 a, f32x4 b) {
    s16x8 r;
    r[0]=f2bf(a[0]); r[1]=f2bf(a[1]); r[2]=f2bf(a[2]); r[3]=f2bf(a[3]);
    r[4]=f2bf(b[0]); r[5]=f2bf(b[1]); r[6]=f2bf(b[2]); r[7]=f2bf(b[3]);
    return r;
}
// packed fp32->bf16 RNE: 1 inst per pair
__device__ __forceinline__ u32 cvtpk_bf16(float a, float b) {
    u32 r;
    asm("v_cvt_pk_bf16_f32 %0, %1, %2" : "=v"(r) : "v"(a), "v"(b));
    return r;
}
// bare 2^x (inputs pre-scaled by log2e at projection/bias-load time)
__device__ __forceinline__ float fexp2(float x) {
    float r;
    asm("v_exp_f32 %0, %1" : "=v"(r) : "v"(x));
    return r;
}
__device__ __forceinline__ void gl_lds16(const void* g, void* l) {
    __builtin_amdgcn_global_load_lds((as1_u32*)(unsigned long long)g,
                                     (as3_u32*)(u32)(unsigned long long)l,
                                     16, 0, 0);
}
// drain ALL outstanding async global->LDS writes of this wave; must precede
// s_barrier so other waves see our staged rows after barrier release.
__device__ __forceinline__ void drain_vmem() {
    asm volatile("s_waitcnt vmcnt(0)" ::: "memory");
}

// ---------------------------------------------------------------------------
// Fused pre-pass (one launch):
//   blocks [0,2304):    xs + prev_k fp32 -> bf16 flat
//   blocks [2304,2432): prev_v -> vbt bf16 [h*64+d][b*4608 + jj]
//   blocks [2432,2624): wt[z*512+n][k] = w_z[k][n] * scale_z, bf16
//   q weights carry an extra log2(e) so attn can use bare v_exp_f32.
// ---------------------------------------------------------------------------
__global__ __launch_bounds__(256, 4)
void prep_kernel(const float* __restrict__ xs, const float* __restrict__ pk,
                 const float* __restrict__ pv, const float* __restrict__ wq,
                 const float* __restrict__ wk, const float* __restrict__ wv,
                 short* __restrict__ xsbf, short* __restrict__ pkbf,
                 short* __restrict__ vbt, short* __restrict__ wt)
{
    __shared__ char smem[17408];
    const int bid = blockIdx.x;
    const int tid = threadIdx.x;

    if (bid < 2304) {
        // ---- convert xs + prev_k ----
        size_t i8 = ((size_t)bid * 256 + tid) * 8;
        const float* src; short* dst; size_t off;
        if (i8 < 4194304) { src = xs; dst = xsbf; off = i8; }
        else              { src = pk; dst = pkbf; off = i8 - 4194304; }
        f32x4 a = *(const f32x4*)(src + off);
        f32x4 b = *(const f32x4*)(src + off + 4);
        *(s16x8*)(dst + off) = pack8(a, b);
    } else if (bid < 2432) {
        // ---- prev_v transpose ----
        short (*st)[72] = (short(*)[72])smem;
        const int b2 = bid - 2304;
        const int jt = b2 & 7, h = (b2 >> 3) & 7, b = b2 >> 6;
        const int jj0 = jt * 64;
        {
            int kk = tid >> 2, d0 = (tid & 3) * 16;
            const float* src = pv + (((size_t)(b * 512 + jj0 + kk)) * 8 + h) * 64 + d0;
            f32x4 x0 = *(const f32x4*)(src);
            f32x4 x1 = *(const f32x4*)(src + 4);
            f32x4 x2 = *(const f32x4*)(src + 8);
            f32x4 x3 = *(const f32x4*)(src + 12);
            *(s16x8*)&st[kk][d0]     = pack8(x0, x1);
            *(s16x8*)&st[kk][d0 + 8] = pack8(x2, x3);
        }
        __syncthreads();
        {
            int dd = tid >> 2, k0 = (tid & 3) * 16;
            s16x8 o0, o1;
            #pragma unroll
            for (int t = 0; t < 8; ++t) { o0[t] = st[k0 + t][dd]; o1[t] = st[k0 + 8 + t][dd]; }
            short* dst = vbt + (size_t)(h * 64 + dd) * 9216 + b * 4608 + jj0 + k0;
            *(s16x8*)dst = o0;
            *(s16x8*)(dst + 8) = o1;
        }
    } else {
        // ---- weight transpose ----
        float (*st)[68] = (float(*)[68])smem;
        const int t2 = bid - 2432;
        const int k0 = (t2 & 7) * 64;
        const int nt = t2 >> 3;
        const int z  = nt >> 3;
        const int n0 = (nt & 7) * 64;
        const float* wz = (z == 0) ? wq : (z == 1) ? wk : wv;
        // q scale folds 1/sqrt(D) AND log2(e) (exp -> exp2 in attn softmax)
        const float scale = (z == 0) ? 0.125f * LOG2E : 1.0f;
        {
            int kk = tid >> 4, nn = (tid & 15) * 4;
            #pragma unroll
            for (int it = 0; it < 4; ++it) {
                f32x4 x = *(const f32x4*)(wz + (size_t)(k0 + kk + it * 16) * 512 + n0 + nn);
                *(f32x4*)&st[kk + it * 16][nn] = x;
            }
        }
        __syncthreads();
        {
            int nn2 = tid >> 2, kseg = (tid & 3) * 16;
            s16x8 o0, o1;
            #pragma unroll
            for (int j = 0; j < 8; ++j) o0[j] = f2bf(st[kseg + j][nn2] * scale);
            #pragma unroll
            for (int j = 0; j < 8; ++j) o1[j] = f2bf(st[kseg + 8 + j][nn2] * scale);
            short* dst = wt + (size_t)(z * 512 + n0 + nn2) * 512 + k0 + kseg;
            *(s16x8*)(dst) = o0;
            *(s16x8*)(dst + 8) = o1;
        }
    }
}

// ---------------------------------------------------------------------------
// Fused QKV projection. z=0/1 -> row-major bf16 q/k; z=2 -> transposed vbt.
// Epilogue also writes next_k/next_v (fp32). Round-0 structure (best
// measured): BK=64 single LDS buffer, drain+barrier / compute / barrier.
// ---------------------------------------------------------------------------
__global__ __launch_bounds__(256, 4)
void proj_kernel(const short* __restrict__ xsbf, const short* __restrict__ wt,
                 short* __restrict__ qkbf, short* __restrict__ vbt,
                 float* __restrict__ out)
{
    __shared__ short Xs[128][64];
    __shared__ short Ws[128][64];

    const int tid = threadIdx.x;
    const int m0  = blockIdx.x * 128;
    const int n0  = blockIdx.y * 128;
    const int z   = n0 >> 9;
    const int ln0 = n0 & 511;
    const int wave = tid >> 6, lane = tid & 63;
    const int wq = (wave & 1) * 64;
    const int wx = (wave >> 1) * 64;
    const int lr = lane & 15, quad = lane >> 4;

    f32x4 acc[4][4] = {};

    const int r8  = lane >> 3;
    const int gr  = lane & 7;

    for (int k0 = 0; k0 < 512; k0 += 64) {
        #pragma unroll
        for (int i = 0; i < 4; ++i) {
            int row = 32 * wave + 8 * i + r8;
            int gs  = gr ^ (row & 7);
            gl_lds16(xsbf + (size_t)(m0 + row) * 512 + k0 + gs * 8, &Xs[32 * wave + 8 * i][0]);
            gl_lds16(wt   + (size_t)(n0 + row) * 512 + k0 + gs * 8, &Ws[32 * wave + 8 * i][0]);
        }
        drain_vmem();
        __syncthreads();
        #pragma unroll
        for (int ks = 0; ks < 2; ++ks) {
            s16x8 af[4], bf[4];
            #pragma unroll
            for (int ta = 0; ta < 4; ++ta) {
                int R = wq + ta * 16 + lr;
                af[ta] = *(const s16x8*)&Ws[R][(((ks * 4 + quad) ^ (R & 7)) * 8)];
            }
            #pragma unroll
            for (int tb = 0; tb < 4; ++tb) {
                int R = wx + tb * 16 + lr;
                bf[tb] = *(const s16x8*)&Xs[R][(((ks * 4 + quad) ^ (R & 7)) * 8)];
            }
            #pragma unroll
            for (int ta = 0; ta < 4; ++ta)
                #pragma unroll
                for (int tb = 0; tb < 4; ++tb)
                    acc[ta][tb] = __builtin_amdgcn_mfma_f32_16x16x32_bf16(
                        af[ta], bf[tb], acc[ta][tb], 0, 0, 0);
        }
        __syncthreads();
    }

    #pragma unroll
    for (int ta = 0; ta < 4; ++ta)
        #pragma unroll
        for (int tb = 0; tb < 4; ++tb) {
            int m  = m0 + wx + tb * 16 + lr;
            int ln = ln0 + wq + ta * 16 + quad * 4;
            int bb = m >> 12, seq = m & 4095;
            if (z < 2) {
                short* base = qkbf + (size_t)z * ((size_t)8192 * 512);
                u32x2 o;
                o[0] = cvtpk_bf16(acc[ta][tb][0], acc[ta][tb][1]);
                o[1] = cvtpk_bf16(acc[ta][tb][2], acc[ta][tb][3]);
                *(u32x2*)(base + (size_t)m * 512 + ln) = o;
                if (z == 1 && seq >= 3584) {
                    float* dst = out + 4194304 + ((size_t)(bb * 512 + seq - 3584)) * 512 + ln;
                    *(f32x4*)dst = acc[ta][tb];
                }
            } else {
                size_t col = (size_t)bb * 4608 + 512 + seq;
                #pragma unroll
                for (int g = 0; g < 4; ++g)
                    vbt[(size_t)(ln + g) * 9216 + col] = f2bf(acc[ta][tb][g]);
                if (seq >= 3584) {
                    float* dst = out + 4194304 + 524288 + ((size_t)(bb * 512 + seq - 3584)) * 512 + ln;
                    *(f32x4*)dst = acc[ta][tb];
                }
            }
        }
}

// ---------------------------------------------------------------------------
// MFMA flash attention, S^T formulation + fixed-max softmax + async staging.
// Block = (b, window n, head h, 128 q rows); 512 thr = 8 waves x 16 q rows.
// Round-0 structure (best measured: 2-buffer, drain+syncthreads, prefetch
// issued after barrier). Micro-opts kept: bare v_exp_f32 (log2e folded into
// q weights + bias table) and v_cvt_pk_bf16_f32 P-packing.
// ---------------------------------------------------------------------------
__global__ __launch_bounds__(512, 4)
void attn_kernel(const short* __restrict__ qkbf, const short* __restrict__ vbt,
                 const short* __restrict__ pkbf, const float* __restrict__ rel_bias,
                 float* __restrict__ out)
{
    __shared__ short k_s[2][64][64];     // [buf][key][d], XOR-swizzled granules
    __shared__ short vt_s[2][64][64];    // [buf][d][key], XOR-swizzled granules
    __shared__ short p_s[128][64];       // per-wave P rows, XOR-swizzled
    __shared__ float bias_s[512];

    const short* qb = qkbf;
    const short* kb = qkbf + (size_t)8192 * 512;

    const int bid = blockIdx.x;
    const int qt = bid & 3;
    const int h  = (bid >> 2) & 7;
    const int n  = (bid >> 5) & 7;
    const int b  = bid >> 8;
    const int tid = threadIdx.x;
    const int wave = tid >> 6, lane = tid & 63;
    const int lr = lane & 15, quad = lane >> 4;
    const int q0 = qt * 128;
    const int i0 = q0 + 16 * wave;

    // T5 bias table (512 entries, one per thread), pre-scaled by log2(e)
    {
        int nd = tid;
        int bucket;
        if (nd < 16) bucket = nd;
        else {
            int vbk = 16 + (int)(log((double)nd * (1.0 / 16.0)) * (16.0 / log(8.0)));
            bucket = vbk < 31 ? vbk : 31;
        }
        bias_s[nd] = rel_bias[h * 32 + bucket] * LOG2E;
    }
    const float bias31 = rel_bias[h * 32 + 31] * LOG2E;

    // Q B-frag direct from global
    s16x8 aq[2];
    {
        const short* src = qb + (size_t)(b * S_ + n * W_ + i0 + lr) * 512 + h * 64 + quad * 8;
        aq[0] = *(const s16x8*)(src);
        aq[1] = *(const s16x8*)(src + 32);
    }

    f32x4 oacc[4] = {};
    float lsum = 0.f;

    const int cmin = (16 * wave) >> 6;
    const int cmax = (16 * wave + 527) >> 6;

    const int r8 = lane >> 3, gr = lane & 7;

    // async staging: wave w stages rows 8w..8w+7 of K chunk and of V^T chunk
    // keys for chunk c are jj in [q0 + 64c, q0 + 64c + 64)  (window coords)
    auto issueKV = [&](int c, int pb) {
        int jj = q0 + 64 * c + 8 * wave + r8;          // key in [q0, q0+640)
        int p  = n * W_ + jj - W_;
        int gs = gr ^ r8;
        const short* ksrc = (p >= 0)
            ? kb   + ((size_t)(b * S_ + p)) * 512 + h * 64 + gs * 8
            : pkbf + (((size_t)(b * W_ + jj)) * 8 + h) * 64 + gs * 8;
        gl_lds16(ksrc, &k_s[pb][8 * wave][0]);
        int drow = 8 * wave + r8;
        const short* vsrc = vbt + (size_t)(h * 64 + drow) * 9216
                          + b * 4608 + n * W_ + q0 + 64 * c + gs * 8;
        gl_lds16(vsrc, &vt_s[pb][8 * wave][0]);
    };

    issueKV(0, 0);

    for (int c = 0; c < 10; ++c) {
        const int pb = c & 1;
        drain_vmem();                    // our async writes land BEFORE barrier
        __syncthreads();                 // now all waves' chunk-c rows are valid
        if (c < 9) issueKV(c + 1, pb ^ 1);   // overlaps compute below
        if (c < cmin || c > cmax) continue;

        // ---- S^T = K * Q^T : D[key][q], col=lane&15=q, row=quad*4+rg=key ----
        f32x4 sacc[4] = {};
        #pragma unroll
        for (int ks = 0; ks < 2; ++ks) {
            s16x8 bk[4];
            #pragma unroll
            for (int tn = 0; tn < 4; ++tn)
                bk[tn] = *(const s16x8*)&k_s[pb][tn * 16 + lr][(((4 * ks + quad) ^ (lr & 7)) * 8)];
            #pragma unroll
            for (int tn = 0; tn < 4; ++tn)
                sacc[tn] = __builtin_amdgcn_mfma_f32_16x16x32_bf16(
                    bk[tn], aq[ks], sacc[tn], 0, 0, 0);
        }

        // ---- bias + mask + exp2 (fixed-max softmax) ----
        const int ib = i0 + lr;          // this lane's q row (window coords)
        const int jb = q0 + 64 * c;
        if (64 * c - 16 * wave <= 336) {
            // all valid pairs have nd >= 113 -> bucket 31 (constant bias)
            #pragma unroll
            for (int tn = 0; tn < 4; ++tn) {
                float pv[4];
                #pragma unroll
                for (int rg = 0; rg < 4; ++rg) {
                    int j = jb + tn * 16 + quad * 4 + rg;
                    unsigned dm1 = (unsigned)(j - ib - 1);
                    float sv = (dm1 < 512u) ? (sacc[tn][rg] + bias31) : MASKV;
                    float p = fexp2(sv);
                    lsum += p;
                    pv[rg] = p;
                }
                u32x2 pp;
                pp[0] = cvtpk_bf16(pv[0], pv[1]);
                pp[1] = cvtpk_bf16(pv[2], pv[3]);
                int gp = (2 * tn + (quad >> 1)) ^ (lr & 7);
                *(u32x2*)&p_s[16 * wave + lr][gp * 8 + (quad & 1) * 4] = pp;
            }
        } else {
            #pragma unroll
            for (int tn = 0; tn < 4; ++tn) {
                float pv[4];
                #pragma unroll
                for (int rg = 0; rg < 4; ++rg) {
                    int j = jb + tn * 16 + quad * 4 + rg;
                    unsigned dm1 = (unsigned)(j - ib - 1);
                    float bias = bias_s[(ib + 512 - j) & 511];
                    float sv = (dm1 < 512u) ? (sacc[tn][rg] + bias) : MASKV;
                    float p = fexp2(sv);
                    lsum += p;
                    pv[rg] = p;
                }
                u32x2 pp;
                pp[0] = cvtpk_bf16(pv[0], pv[1]);
                pp[1] = cvtpk_bf16(pv[2], pv[3]);
                int gp = (2 * tn + (quad >> 1)) ^ (lr & 7);
                *(u32x2*)&p_s[16 * wave + lr][gp * 8 + (quad & 1) * 4] = pp;
            }
        }

        asm volatile("s_waitcnt lgkmcnt(0)" ::: "memory");

        // ---- O += P V : A=P (q x keys), B=V (keys x d) ----
        #pragma unroll
        for (int ks = 0; ks < 2; ++ks) {
            int gpa = (4 * ks + quad) ^ (lr & 7);
            s16x8 ap = *(const s16x8*)&p_s[16 * wave + lr][gpa * 8];
            s16x8 bv[4];
            #pragma unroll
            for (int tn = 0; tn < 4; ++tn)
                bv[tn] = *(const s16x8*)&vt_s[pb][tn * 16 + lr][(((4 * ks + quad) ^ (lr & 7)) * 8)];
            #pragma unroll
            for (int tn = 0; tn < 4; ++tn)
                oacc[tn] = __builtin_amdgcn_mfma_f32_16x16x32_bf16(
                    ap, bv[tn], oacc[tn], 0, 0, 0);
        }
    }

    // ---- final l reduction over quads; redistribute; store ----
    lsum += __shfl_xor(lsum, 16);
    lsum += __shfl_xor(lsum, 32);
    float linv[4];
    #pragma unroll
    for (int rg = 0; rg < 4; ++rg)
        linv[rg] = 1.0f / __shfl(lsum, quad * 4 + rg);

    #pragma unroll
    for (int rg = 0; rg < 4; ++rg) {
        int row = i0 + quad * 4 + rg;
        float* dst = out + (((size_t)b * S_ + n * W_ + row) * H_ + h) * D_ + lr;
        #pragma unroll
        for (int tn = 0; tn < 4; ++tn)
            dst[tn * 16] = oacc[tn][rg] * linv[rg];
    }
}

extern "C" void kernel_launch(void* const* d_in, const int* in_sizes, int n_in,
                              void* d_out, int out_size, void* d_ws, size_t ws_size,
                              hipStream_t stream)
{
    const float* xs       = (const float*)d_in[0];
    const float* prev_k   = (const float*)d_in[1];
    const float* prev_v   = (const float*)d_in[2];
    const float* w_q      = (const float*)d_in[3];
    const float* w_k      = (const float*)d_in[4];
    const float* w_v      = (const float*)d_in[5];
    const float* rel_bias = (const float*)d_in[6];
    float* out = (float*)d_out;

    short* xsbf = (short*)d_ws;                         // 4,194,304
    short* wt   = xsbf + (size_t)4194304;               //   786,432
    short* qkbf = wt   + (size_t)786432;                // 8,388,608 (q then k)
    short* pkbf = qkbf + (size_t)8388608;               //   524,288
    short* vbt  = pkbf + (size_t)524288;                // 512 x 9216

    prep_kernel<<<2624, 256, 0, stream>>>(xs, prev_k, prev_v, w_q, w_k, w_v,
                                          xsbf, pkbf, vbt, wt);

    proj_kernel<<<dim3(64, 12), 256, 0, stream>>>(xsbf, wt, qkbf, vbt, out);

    attn_kernel<<<512, 512, 0, stream>>>(qkbf, vbt, pkbf, rel_bias, out);
}